// Round 10
// baseline (5466.347 us; speedup 1.0000x reference)
//
#include <hip/hip_runtime.h>

#define TT 512
#define NN 64
#define DD 1024
#define HH 1024
#define NSLOT 32

typedef __attribute__((ext_vector_type(8))) short bf16x8;
typedef __attribute__((ext_vector_type(4))) float f32x4;
typedef __attribute__((ext_vector_type(8))) unsigned short u16x8;
typedef __attribute__((ext_vector_type(4))) int i32x4;
typedef __attribute__((ext_vector_type(2))) int i32x2;

// ---- static device buffers (rewritten every launch by prep/gemm) ----
// fragment-tiled bf16: vec8 idx = (tile*32 + kk)*64 + lane, elem e:
//   matrix[col = tile*16 + (lane&15)][k = kk*32 + (lane>>4)*8 + e]
__device__ unsigned short g_wih[192u * 2048 * 8];            // 6 MB
__device__ unsigned short g_whh[192u * 2048 * 8];            // 6 MB
__device__ unsigned short g_x[2048u * 2048 * 8];             // 67 MB, tile=(t*4+eg)
// gi (x-projection, bf16): [(t*4+eg)*64 + jg][gate][env16][jj16]
__device__ unsigned short g_gi[(size_t)2048 * 64 * 768];     // 201 MB
// tagged h state, NSLOT rotating slots: word=(tag<<16)|bf16(h); [slot][eg][16384]
__device__ unsigned g_hbuf32[(size_t)NSLOT * 4 * 16384];     // 8 MB
// per-wave ordered signals: [slot][eg][jg*4 + wave] (tag value)
__device__ int g_sig[NSLOT * 4 * 256];                       // 128 KB

__device__ __forceinline__ unsigned short f2bf(float f) {
  unsigned u = __float_as_uint(f);
  u += 0x7fffu + ((u >> 16) & 1u);
  return (unsigned short)(u >> 16);
}

__global__ void prep_kernel(const float* __restrict__ x,
                            const float* __restrict__ wih,
                            const float* __restrict__ whh) {
  const int gsz = gridDim.x * blockDim.x;
  const int gid = blockIdx.x * blockDim.x + threadIdx.x;
  // zero tag buffer + signals (tag 0 = invalid; live tags are 1..513)
  for (int z = gid; z < NSLOT * 4 * 16384; z += gsz) g_hbuf32[z] = 0u;
  for (int z = gid; z < NSLOT * 4 * 256; z += gsz) g_sig[z] = 0;

  const int W8 = 192 * 2048;          // vec8 groups per weight matrix
  const int X8 = 2048 * 2048;         // vec8 groups for x
  for (int idx = gid; idx < 2 * W8 + X8; idx += gsz) {
    if (idx < 2 * W8) {
      const float* src = (idx < W8) ? wih : whh;
      unsigned short* dst = (idx < W8) ? g_wih : g_whh;
      int i8 = (idx < W8) ? idx : idx - W8;
      size_t g = (size_t)i8 * 8;
      int col = (int)(g >> 10);
      int k = (int)(g & 1023);
      int kk = k >> 5, lg = (k >> 3) & 3;
      int cg = col >> 4;
      int l = (col & 15) | (lg << 4);
      size_t o8 = ((size_t)cg * 32 + kk) * 64 + l;
      const float* p = src + g;
      float4 v0 = *(const float4*)(p);
      float4 v1 = *(const float4*)(p + 4);
      u16x8 u;
      u[0] = f2bf(v0.x); u[1] = f2bf(v0.y); u[2] = f2bf(v0.z); u[3] = f2bf(v0.w);
      u[4] = f2bf(v1.x); u[5] = f2bf(v1.y); u[6] = f2bf(v1.z); u[7] = f2bf(v1.w);
      *(u16x8*)(dst + o8 * 8) = u;
    } else {
      int i8 = idx - 2 * W8;
      size_t g = (size_t)i8 * 8;
      int row = (int)(g >> 10);             // t*64 + env
      int k = (int)(g & 1023);
      int t = row >> 6, env = row & 63;
      int eg = env >> 4;
      int kk = k >> 5, lg = (k >> 3) & 3;
      int l = (env & 15) | (lg << 4);
      size_t o8 = (((size_t)t * 4 + eg) * 32 + kk) * 64 + l;
      const float* p = x + g;
      float4 v0 = *(const float4*)(p);
      float4 v1 = *(const float4*)(p + 4);
      u16x8 u;
      u[0] = f2bf(v0.x); u[1] = f2bf(v0.y); u[2] = f2bf(v0.z); u[3] = f2bf(v0.w);
      u[4] = f2bf(v1.x); u[5] = f2bf(v1.y); u[6] = f2bf(v1.z); u[7] = f2bf(v1.w);
      *(u16x8*)(g_x + o8 * 8) = u;
    }
  }
}

// ---- gi = x * wih^T, 128x128 tile, BK=128, reg-prefetch + LDS ----
__global__ __launch_bounds__(256) void gemm_gi() {
  extern __shared__ char smem[];
  unsigned short* As = (unsigned short*)smem;      // 32KB
  unsigned short* Bs = As + 2048 * 8;              // 32KB
  const int tid = threadIdx.x;
  const int bid = blockIdx.x;
  const int mblk = bid & 255, nblk = bid >> 8;     // 256 x 24
  const int w = tid >> 6, l = tid & 63;
  const int wm = w >> 1, wn = w & 1;

  u16x8 pa[8], pb[8];
  #pragma unroll
  for (int i = 0; i < 8; ++i) {
    int e = tid + i * 256;
    int mt = e >> 8, kkl = (e >> 6) & 3, lane = e & 63;
    pa[i] = *((const u16x8*)g_x  + ((size_t)(mblk * 8 + mt) * 32 + kkl) * 64 + lane);
    pb[i] = *((const u16x8*)g_wih + ((size_t)(nblk * 8 + mt) * 32 + kkl) * 64 + lane);
  }
  f32x4 acc[4][4] = {};
  for (int c = 0; c < 8; ++c) {
    __syncthreads();
    #pragma unroll
    for (int i = 0; i < 8; ++i) {
      int e = tid + i * 256;
      ((u16x8*)As)[e] = pa[i];
      ((u16x8*)Bs)[e] = pb[i];
    }
    __syncthreads();
    if (c < 7) {
      #pragma unroll
      for (int i = 0; i < 8; ++i) {
        int e = tid + i * 256;
        int mt = e >> 8, kkl = (e >> 6) & 3, lane = e & 63;
        pa[i] = *((const u16x8*)g_x  + ((size_t)(mblk * 8 + mt) * 32 + (c + 1) * 4 + kkl) * 64 + lane);
        pb[i] = *((const u16x8*)g_wih + ((size_t)(nblk * 8 + mt) * 32 + (c + 1) * 4 + kkl) * 64 + lane);
      }
    }
    #pragma unroll
    for (int kkl = 0; kkl < 4; ++kkl) {
      bf16x8 af[4], bfr[4];
      #pragma unroll
      for (int ai = 0; ai < 4; ++ai) af[ai]  = ((const bf16x8*)As)[((wm * 4 + ai) * 4 + kkl) * 64 + l];
      #pragma unroll
      for (int bi = 0; bi < 4; ++bi) bfr[bi] = ((const bf16x8*)Bs)[((wn * 4 + bi) * 4 + kkl) * 64 + l];
      #pragma unroll
      for (int ai = 0; ai < 4; ++ai)
        #pragma unroll
        for (int bi = 0; bi < 4; ++bi)
          acc[ai][bi] = __builtin_amdgcn_mfma_f32_16x16x32_bf16(af[ai], bfr[bi], acc[ai][bi], 0, 0, 0);
    }
  }
  const int jj = l & 15;
  #pragma unroll
  for (int ai = 0; ai < 4; ++ai)
    #pragma unroll
    for (int bi = 0; bi < 4; ++bi) {
      int mt = mblk * 8 + wm * 4 + ai;       // = t*4+eg
      int nt = nblk * 8 + wn * 4 + bi;
      int gate = nt >> 6, jg = nt & 63;
      size_t base = ((size_t)mt * 64 + jg) * 768 + (size_t)gate * 256;
      #pragma unroll
      for (int i = 0; i < 4; ++i) {
        int env = (l >> 4) * 4 + i;
        g_gi[base + env * 16 + jj] = f2bf(acc[ai][bi][i]);
      }
    }
}

// ---- persistent scan: 256 wgs = (eg 0..3) x (jg 0..63), 1 wg/CU ----
__global__ __launch_bounds__(256) void scan_kernel(const float* __restrict__ hx,
                                                   const float* __restrict__ mask,
                                                   const float* __restrict__ bih,
                                                   const float* __restrict__ bhh,
                                                   float* __restrict__ out) {
  extern __shared__ char smem[];
  unsigned short* whhL = (unsigned short*)smem;          // 96KB
  unsigned short* hA   = whhL + 3 * 2048 * 8;            // 32KB
  float* Cl = (float*)(hA + 2048 * 8);                   // 3KB
  __shared__ int sFlag;                                  // poll broadcast

  const int tid = threadIdx.x;
  const int bid = blockIdx.x;
  const int eg = bid >> 6, jg = bid & 63;
  const int e0 = eg * 16;
  const int w3 = tid >> 6, l = tid & 63;
  const int e_ = tid >> 4, jj = tid & 15;
  const int j = jg * 16 + jj;

  // preload W_hh j-slice into LDS (gates r,z,n)
  #pragma unroll 4
  for (int i = 0; i < 24; ++i) {
    int e = tid + i * 256;                   // < 6144
    int gate = e >> 11, rem = e & 2047;
    ((u16x8*)whhL)[e] = *((const u16x8*)g_whh + (size_t)(gate * 64 + jg) * 2048 + rem);
  }

  // producer word index for this thread's h[e0+e_][j] in fragment order
  const int kf = jg * 16 + jj;
  const int widx = (((kf >> 5) * 64) + (e_ | (((kf >> 3) & 3) << 4))) * 8 + (kf & 7);

  // publish h0 = hx*mask[0] with tag 1 into slot 0; wave-ordered signal
  float hreg;
  {
    float h0 = hx[(size_t)(e0 + e_) * HH + j] * mask[e0 + e_];
    hreg = h0;
    unsigned tw = (1u << 16) | (unsigned)f2bf(h0);
    unsigned* dst = g_hbuf32 + ((size_t)eg << 14) + widx;
    asm volatile("global_store_dword %0, %1, off sc0 sc1" :: "v"(dst), "v"(tw) : "memory");
  }
  asm volatile("s_waitcnt vmcnt(0)" ::: "memory");   // this wave's h0 ack'd
  if (l == 0) {
    int* sp0 = g_sig + (eg << 8) + (jg << 2) + w3;
    int one = 1;
    asm volatile("global_store_dword %0, %1, off sc0 sc1" :: "v"(sp0), "v"(one) : "memory");
  }
  if (tid == 0) sFlag = 0;
  __syncthreads();

  const float br  = bih[j] + bhh[j];
  const float bz  = bih[HH + j] + bhh[HH + j];
  const float bin = bih[2 * HH + j];
  const float bhn = bhh[2 * HH + j];

  // gi prefetch, depth 2 (pg0 = step t, pg1 = step t+1)
  unsigned short pgr0, pgz0, pgn0, pgr1, pgz1, pgn1;
  {
    size_t gb0 = ((size_t)eg * 64 + jg) * 768;
    pgr0 = g_gi[gb0 + tid]; pgz0 = g_gi[gb0 + 256 + tid]; pgn0 = g_gi[gb0 + 512 + tid];
    size_t gb1 = ((size_t)(4 + eg) * 64 + jg) * 768;
    pgr1 = g_gi[gb1 + tid]; pgz1 = g_gi[gb1 + 256 + tid]; pgn1 = g_gi[gb1 + 512 + tid];
  }

  const unsigned voff = (unsigned)tid * 16;  // byte offset for dwordx4

  for (int t = 0; t < TT; ++t) {
    int tm = (t + 1 < TT) ? (t + 1) : (TT - 1);
    float mnext = mask[tm * NN + e0 + e_];

    const int slot = t & (NSLOT - 1);
    const unsigned* hb = g_hbuf32 + (((size_t)slot * 4 + eg) << 14);
    const unsigned tagc = (unsigned)(t + 1);

    // ---- poll: wave0 watches the 1KB ordered-signal block; LDS broadcast ----
    if (w3 == 0) {
      const int* sp = g_sig + ((slot * 4 + eg) << 8) + (l << 2);
      while (true) {
        i32x4 sv;
        asm volatile("global_load_dwordx4 %0, %1, off sc0 sc1\n\t"
                     "s_waitcnt vmcnt(0)"
                     : "=v"(sv) : "v"(sp) : "memory");
        int mn = min(min(sv[0], sv[1]), min(sv[2], sv[3]));
        if (__all(mn >= (int)tagc)) break;
        __builtin_amdgcn_s_sleep(1);
      }
      if (tid == 0) *((volatile int*)&sFlag) = (int)tagc;
    } else {
      volatile int* vf = &sFlag;
      while (*vf < (int)tagc) __builtin_amdgcn_s_sleep(1);
    }
    __builtin_amdgcn_sched_barrier(0);

    // ---- attempt 1: PLAIN cached bulk read (fresh by signal ordering; L2-shared) ----
    const unsigned tagp = tagc << 16;
    const i32x4* hp = (const i32x4*)hb + tid;
    i32x4 hv[16];
    #pragma unroll
    for (int c = 0; c < 16; ++c) hv[c] = hp[c * 256];

    unsigned stale = 0;
    #pragma unroll
    for (int c = 0; c < 16; ++c) {
      unsigned bad = (((unsigned)hv[c][0] ^ tagp) | ((unsigned)hv[c][1] ^ tagp) |
                      ((unsigned)hv[c][2] ^ tagp) | ((unsigned)hv[c][3] ^ tagp)) & 0xFFFF0000u;
      if (bad) stale |= (1u << c);
      else {
        i32x2 pk;
        pk[0] = (int)__builtin_amdgcn_perm((unsigned)hv[c][1], (unsigned)hv[c][0], 0x05040100u);
        pk[1] = (int)__builtin_amdgcn_perm((unsigned)hv[c][3], (unsigned)hv[c][2], 0x05040100u);
        ((i32x2*)hA)[c * 256 + tid] = pk;
      }
    }
    // ---- escalation: only stale chunks (slot-reuse L2 lines), coherent path ----
    while (__any(stale != 0)) {
      #pragma unroll
      for (int c = 0; c < 16; ++c) if (stale & (1u << c)) {
        asm volatile("global_load_dwordx4 %0, %1, %2 sc0 sc1"
                     : "=v"(hv[c]) : "v"(voff), "s"((const void*)(hb + c * 1024)));
      }
      asm volatile("s_waitcnt vmcnt(0)" ::: "memory");
      __builtin_amdgcn_sched_barrier(0);
      #pragma unroll
      for (int c = 0; c < 16; ++c) if (stale & (1u << c)) {
        unsigned bad = (((unsigned)hv[c][0] ^ tagp) | ((unsigned)hv[c][1] ^ tagp) |
                        ((unsigned)hv[c][2] ^ tagp) | ((unsigned)hv[c][3] ^ tagp)) & 0xFFFF0000u;
        if (!bad) {
          i32x2 pk;
          pk[0] = (int)__builtin_amdgcn_perm((unsigned)hv[c][1], (unsigned)hv[c][0], 0x05040100u);
          pk[1] = (int)__builtin_amdgcn_perm((unsigned)hv[c][3], (unsigned)hv[c][2], 0x05040100u);
          ((i32x2*)hA)[c * 256 + tid] = pk;
          stale &= ~(1u << c);
        }
      }
    }
    __syncthreads();

    // consume gi(t) from pg0; shift pg1->pg0; issue gi(t+2) into pg1
    float gr  = __uint_as_float((unsigned)pgr0 << 16);
    float gz  = __uint_as_float((unsigned)pgz0 << 16);
    float gn_ = __uint_as_float((unsigned)pgn0 << 16);
    pgr0 = pgr1; pgz0 = pgz1; pgn0 = pgn1;
    {
      int t2 = (t + 2 < TT) ? (t + 2) : (TT - 1);
      size_t gb = ((size_t)(t2 * 4 + eg) * 64 + jg) * 768;
      pgr1 = g_gi[gb + tid]; pgz1 = g_gi[gb + 256 + tid]; pgn1 = g_gi[gb + 512 + tid];
    }

    // ---- h-GEMM: wave w3 in {0,1,2} computes gate tile (r, z, h_n) ----
    if (w3 < 3) {
      const bf16x8* ap = (const bf16x8*)hA;
      const bf16x8* bp = (const bf16x8*)whhL + (size_t)w3 * 2048;
      f32x4 a0 = {0.f,0.f,0.f,0.f}, a1 = {0.f,0.f,0.f,0.f};
      f32x4 a2 = {0.f,0.f,0.f,0.f}, a3 = {0.f,0.f,0.f,0.f};
      #pragma unroll 8
      for (int kk = 0; kk < 8; ++kk) {
        a0 = __builtin_amdgcn_mfma_f32_16x16x32_bf16(ap[kk * 64 + l],        bp[kk * 64 + l],        a0, 0, 0, 0);
        a1 = __builtin_amdgcn_mfma_f32_16x16x32_bf16(ap[(kk + 8) * 64 + l],  bp[(kk + 8) * 64 + l],  a1, 0, 0, 0);
        a2 = __builtin_amdgcn_mfma_f32_16x16x32_bf16(ap[(kk + 16) * 64 + l], bp[(kk + 16) * 64 + l], a2, 0, 0, 0);
        a3 = __builtin_amdgcn_mfma_f32_16x16x32_bf16(ap[(kk + 24) * 64 + l], bp[(kk + 24) * 64 + l], a3, 0, 0, 0);
      }
      f32x4 s;
      #pragma unroll
      for (int i = 0; i < 4; ++i) s[i] = (a0[i] + a1[i]) + (a2[i] + a3[i]);
      int col = l & 15, r0 = (l >> 4) * 4;
      #pragma unroll
      for (int i = 0; i < 4; ++i) Cl[w3 * 256 + (r0 + i) * 16 + col] = s[i];
    }
    __syncthreads();

    // ---- elementwise GRU update; publish h(t+1), wave-ordered signal, out ----
    {
      float pr = gr + Cl[tid] + br;
      float pz = gz + Cl[256 + tid] + bz;
      float r = 1.f / (1.f + __expf(-pr));
      float z = 1.f / (1.f + __expf(-pz));
      float hn = Cl[512 + tid] + bhn;
      float gn = gn_ + bin + r * hn;
      float e2g = __expf(2.f * gn);
      float n = 1.f - 2.f / (e2g + 1.f);
      float hnew = (1.f - z) * n + z * hreg;

      if (t + 1 < TT) {
        float hm = hnew * mnext;
        hreg = hm;
        unsigned tw = ((unsigned)(t + 2) << 16) | (unsigned)f2bf(hm);
        unsigned* dst = g_hbuf32 + ((((size_t)((t + 1) & (NSLOT - 1))) * 4 + eg) << 14) + widx;
        asm volatile("global_store_dword %0, %1, off sc0 sc1" :: "v"(dst), "v"(tw) : "memory");
        asm volatile("s_waitcnt vmcnt(0)" ::: "memory");   // this wave's h ack'd
        if (l == 0) {
          int* sp = g_sig + ((((t + 1) & (NSLOT - 1)) * 4 + eg) << 8) + (jg << 2) + w3;
          int tv = t + 2;
          asm volatile("global_store_dword %0, %1, off sc0 sc1" :: "v"(sp), "v"(tv) : "memory");
        }
      }

      out[(size_t)t * NN * HH + (size_t)(e0 + e_) * HH + j] = hnew;
      if (t == TT - 1)
        out[(size_t)TT * NN * HH + (size_t)(e0 + e_) * HH + j] = hnew;
    }
  }
}

extern "C" void kernel_launch(void* const* d_in, const int* in_sizes, int n_in,
                              void* d_out, int out_size, void* d_ws, size_t ws_size,
                              hipStream_t stream) {
  (void)in_sizes; (void)n_in; (void)d_ws; (void)ws_size; (void)out_size;
  const float* x    = (const float*)d_in[0];
  const float* hx   = (const float*)d_in[1];
  const float* mask = (const float*)d_in[2];
  const float* wih  = (const float*)d_in[3];
  const float* whh  = (const float*)d_in[4];
  const float* bih  = (const float*)d_in[5];
  const float* bhh  = (const float*)d_in[6];
  float* out = (float*)d_out;

  hipFuncSetAttribute((const void*)gemm_gi, hipFuncAttributeMaxDynamicSharedMemorySize, 65536);
  hipFuncSetAttribute((const void*)scan_kernel, hipFuncAttributeMaxDynamicSharedMemorySize, 134144);

  prep_kernel<<<2048, 256, 0, stream>>>(x, wih, whh);
  gemm_gi<<<6144, 256, 65536, stream>>>();
  scan_kernel<<<256, 256, 134144, stream>>>(hx, mask, bih, bhh, out);
}

// Round 11
// 4830.605 us; speedup vs baseline: 1.1316x; 1.1316x over previous
//
#include <hip/hip_runtime.h>

#define TT 512
#define NN 64
#define DD 1024
#define HH 1024
#define NSLOT 64

typedef __attribute__((ext_vector_type(8))) short bf16x8;
typedef __attribute__((ext_vector_type(4))) float f32x4;
typedef __attribute__((ext_vector_type(8))) unsigned short u16x8;
typedef __attribute__((ext_vector_type(4))) int i32x4;
typedef __attribute__((ext_vector_type(2))) int i32x2;

// ---- static device buffers (rewritten every launch by prep/gemm) ----
// fragment-tiled bf16: vec8 idx = (tile*32 + kk)*64 + lane, elem e:
//   matrix[col = tile*16 + (lane&15)][k = kk*32 + (lane>>4)*8 + e]
__device__ unsigned short g_wih[192u * 2048 * 8];            // 6 MB
__device__ unsigned short g_whh[192u * 2048 * 8];            // 6 MB
__device__ unsigned short g_x[2048u * 2048 * 8];             // 67 MB, tile=(t*4+eg)
// gi (x-projection, bf16): [(t*4+eg)*64 + jg][gate][env16][jj16]
__device__ unsigned short g_gi[(size_t)2048 * 64 * 768];     // 201 MB
// tagged h state, NSLOT rotating slots: word=(tag<<16)|bf16(h); [slot][eg][16384]
__device__ unsigned g_hbuf32[(size_t)NSLOT * 4 * 16384];     // 16 MB

__device__ __forceinline__ unsigned short f2bf(float f) {
  unsigned u = __float_as_uint(f);
  u += 0x7fffu + ((u >> 16) & 1u);
  return (unsigned short)(u >> 16);
}

__global__ void prep_kernel(const float* __restrict__ x,
                            const float* __restrict__ wih,
                            const float* __restrict__ whh) {
  const int gsz = gridDim.x * blockDim.x;
  const int gid = blockIdx.x * blockDim.x + threadIdx.x;
  // zero the rotating tag buffer (tag 0 = invalid; live tags are 1..513)
  for (int z = gid; z < NSLOT * 4 * 16384; z += gsz) g_hbuf32[z] = 0u;

  const int W8 = 192 * 2048;          // vec8 groups per weight matrix
  const int X8 = 2048 * 2048;         // vec8 groups for x
  for (int idx = gid; idx < 2 * W8 + X8; idx += gsz) {
    if (idx < 2 * W8) {
      const float* src = (idx < W8) ? wih : whh;
      unsigned short* dst = (idx < W8) ? g_wih : g_whh;
      int i8 = (idx < W8) ? idx : idx - W8;
      size_t g = (size_t)i8 * 8;
      int col = (int)(g >> 10);
      int k = (int)(g & 1023);
      int kk = k >> 5, lg = (k >> 3) & 3;
      int cg = col >> 4;
      int l = (col & 15) | (lg << 4);
      size_t o8 = ((size_t)cg * 32 + kk) * 64 + l;
      const float* p = src + g;
      float4 v0 = *(const float4*)(p);
      float4 v1 = *(const float4*)(p + 4);
      u16x8 u;
      u[0] = f2bf(v0.x); u[1] = f2bf(v0.y); u[2] = f2bf(v0.z); u[3] = f2bf(v0.w);
      u[4] = f2bf(v1.x); u[5] = f2bf(v1.y); u[6] = f2bf(v1.z); u[7] = f2bf(v1.w);
      *(u16x8*)(dst + o8 * 8) = u;
    } else {
      int i8 = idx - 2 * W8;
      size_t g = (size_t)i8 * 8;
      int row = (int)(g >> 10);             // t*64 + env
      int k = (int)(g & 1023);
      int t = row >> 6, env = row & 63;
      int eg = env >> 4;
      int kk = k >> 5, lg = (k >> 3) & 3;
      int l = (env & 15) | (lg << 4);
      size_t o8 = (((size_t)t * 4 + eg) * 32 + kk) * 64 + l;
      const float* p = x + g;
      float4 v0 = *(const float4*)(p);
      float4 v1 = *(const float4*)(p + 4);
      u16x8 u;
      u[0] = f2bf(v0.x); u[1] = f2bf(v0.y); u[2] = f2bf(v0.z); u[3] = f2bf(v0.w);
      u[4] = f2bf(v1.x); u[5] = f2bf(v1.y); u[6] = f2bf(v1.z); u[7] = f2bf(v1.w);
      *(u16x8*)(g_x + o8 * 8) = u;
    }
  }
}

// ---- gi = x * wih^T, 128x128 tile, BK=128, reg-prefetch + LDS ----
__global__ __launch_bounds__(256) void gemm_gi() {
  extern __shared__ char smem[];
  unsigned short* As = (unsigned short*)smem;      // 32KB
  unsigned short* Bs = As + 2048 * 8;              // 32KB
  const int tid = threadIdx.x;
  const int bid = blockIdx.x;
  const int mblk = bid & 255, nblk = bid >> 8;     // 256 x 24
  const int w = tid >> 6, l = tid & 63;
  const int wm = w >> 1, wn = w & 1;

  u16x8 pa[8], pb[8];
  #pragma unroll
  for (int i = 0; i < 8; ++i) {
    int e = tid + i * 256;
    int mt = e >> 8, kkl = (e >> 6) & 3, lane = e & 63;
    pa[i] = *((const u16x8*)g_x  + ((size_t)(mblk * 8 + mt) * 32 + kkl) * 64 + lane);
    pb[i] = *((const u16x8*)g_wih + ((size_t)(nblk * 8 + mt) * 32 + kkl) * 64 + lane);
  }
  f32x4 acc[4][4] = {};
  for (int c = 0; c < 8; ++c) {
    __syncthreads();
    #pragma unroll
    for (int i = 0; i < 8; ++i) {
      int e = tid + i * 256;
      ((u16x8*)As)[e] = pa[i];
      ((u16x8*)Bs)[e] = pb[i];
    }
    __syncthreads();
    if (c < 7) {
      #pragma unroll
      for (int i = 0; i < 8; ++i) {
        int e = tid + i * 256;
        int mt = e >> 8, kkl = (e >> 6) & 3, lane = e & 63;
        pa[i] = *((const u16x8*)g_x  + ((size_t)(mblk * 8 + mt) * 32 + (c + 1) * 4 + kkl) * 64 + lane);
        pb[i] = *((const u16x8*)g_wih + ((size_t)(nblk * 8 + mt) * 32 + (c + 1) * 4 + kkl) * 64 + lane);
      }
    }
    #pragma unroll
    for (int kkl = 0; kkl < 4; ++kkl) {
      bf16x8 af[4], bfr[4];
      #pragma unroll
      for (int ai = 0; ai < 4; ++ai) af[ai]  = ((const bf16x8*)As)[((wm * 4 + ai) * 4 + kkl) * 64 + l];
      #pragma unroll
      for (int bi = 0; bi < 4; ++bi) bfr[bi] = ((const bf16x8*)Bs)[((wn * 4 + bi) * 4 + kkl) * 64 + l];
      #pragma unroll
      for (int ai = 0; ai < 4; ++ai)
        #pragma unroll
        for (int bi = 0; bi < 4; ++bi)
          acc[ai][bi] = __builtin_amdgcn_mfma_f32_16x16x32_bf16(af[ai], bfr[bi], acc[ai][bi], 0, 0, 0);
    }
  }
  const int jj = l & 15;
  #pragma unroll
  for (int ai = 0; ai < 4; ++ai)
    #pragma unroll
    for (int bi = 0; bi < 4; ++bi) {
      int mt = mblk * 8 + wm * 4 + ai;       // = t*4+eg
      int nt = nblk * 8 + wn * 4 + bi;
      int gate = nt >> 6, jg = nt & 63;
      size_t base = ((size_t)mt * 64 + jg) * 768 + (size_t)gate * 256;
      #pragma unroll
      for (int i = 0; i < 4; ++i) {
        int env = (l >> 4) * 4 + i;
        g_gi[base + env * 16 + jj] = f2bf(acc[ai][bi][i]);
      }
    }
}

// ---- persistent scan: 256 wgs = (eg 0..3) x (jg 0..63), 1 wg/CU ----
__global__ __launch_bounds__(256) void scan_kernel(const float* __restrict__ hx,
                                                   const float* __restrict__ mask,
                                                   const float* __restrict__ bih,
                                                   const float* __restrict__ bhh,
                                                   float* __restrict__ out) {
  extern __shared__ char smem[];
  unsigned short* whhL = (unsigned short*)smem;          // 96KB
  unsigned short* hA   = whhL + 3 * 2048 * 8;            // 32KB
  float* Cl = (float*)(hA + 2048 * 8);                   // 3KB
  __shared__ int sFlag;                                  // poll broadcast (LDS)

  const int tid = threadIdx.x;
  const int bid = blockIdx.x;
  const int eg = bid >> 6, jg = bid & 63;
  const int e0 = eg * 16;
  const int w3 = tid >> 6, l = tid & 63;
  const int e_ = tid >> 4, jj = tid & 15;
  const int j = jg * 16 + jj;

  // preload W_hh j-slice into LDS (gates r,z,n)
  #pragma unroll 4
  for (int i = 0; i < 24; ++i) {
    int e = tid + i * 256;                   // < 6144
    int gate = e >> 11, rem = e & 2047;
    ((u16x8*)whhL)[e] = *((const u16x8*)g_whh + (size_t)(gate * 64 + jg) * 2048 + rem);
  }

  // producer word index for this thread's h[e0+e_][j] in fragment order.
  // Closed form: tid 0 of producer wg jg' lands at word 256*jg' (poll target).
  const int kf = jg * 16 + jj;
  const int widx = (((kf >> 5) * 64) + (e_ | (((kf >> 3) & 3) << 4))) * 8 + (kf & 7);

  // publish h0 = hx*mask[0] with tag 1 into slot 0 (fire-and-forget)
  float hreg;
  {
    float h0 = hx[(size_t)(e0 + e_) * HH + j] * mask[e0 + e_];
    hreg = h0;
    unsigned tw = (1u << 16) | (unsigned)f2bf(h0);
    unsigned* dst = g_hbuf32 + ((size_t)eg << 14) + widx;
    asm volatile("global_store_dword %0, %1, off sc0 sc1" :: "v"(dst), "v"(tw) : "memory");
  }
  if (tid == 0) sFlag = 0;
  __syncthreads();

  const float br  = bih[j] + bhh[j];
  const float bz  = bih[HH + j] + bhh[HH + j];
  const float bin = bih[2 * HH + j];
  const float bhn = bhh[2 * HH + j];

  // gi prefetch, depth 2 (pg0 = step t, pg1 = step t+1)
  unsigned short pgr0, pgz0, pgn0, pgr1, pgz1, pgn1;
  {
    size_t gb0 = ((size_t)eg * 64 + jg) * 768;
    pgr0 = g_gi[gb0 + tid]; pgz0 = g_gi[gb0 + 256 + tid]; pgn0 = g_gi[gb0 + 512 + tid];
    size_t gb1 = ((size_t)(4 + eg) * 64 + jg) * 768;
    pgr1 = g_gi[gb1 + tid]; pgz1 = g_gi[gb1 + 256 + tid]; pgn1 = g_gi[gb1 + 512 + tid];
  }

  const unsigned voff = (unsigned)tid * 16;  // byte offset for dwordx4

  for (int t = 0; t < TT; ++t) {
    int tm = (t + 1 < TT) ? (t + 1) : (TT - 1);
    float mnext = mask[tm * NN + e0 + e_];

    const int slot = t & (NSLOT - 1);
    const unsigned* hb = g_hbuf32 + (((size_t)slot * 4 + eg) << 14);
    const unsigned tagc = (unsigned)(t + 1);

    // ---- poll the DATA, wave0 only: lane l watches producer jg'=l's
    //      tid-0 tagged word; waves 1-3 wait on LDS flag (no fabric) ----
    if (w3 == 0) {
      const unsigned* pp = hb + (l << 8);
      while (true) {
        unsigned v;
        asm volatile("global_load_dword %0, %1, off sc0 sc1\n\t"
                     "s_waitcnt vmcnt(0)"
                     : "=v"(v) : "v"(pp) : "memory");
        if (__all((v >> 16) >= tagc)) break;
        __builtin_amdgcn_s_sleep(1);
      }
      if (l == 0) *((volatile int*)&sFlag) = (int)tagc;
    } else {
      volatile int* vf = &sFlag;
      while (*vf < (int)tagc) __builtin_amdgcn_s_sleep(1);
    }
    __builtin_amdgcn_sched_barrier(0);

    // ---- attempt 1: PLAIN cached bulk read (L2-shared across same-XCD peers) ----
    const unsigned tagp = tagc << 16;
    const i32x4* hp = (const i32x4*)hb + tid;
    i32x4 hv[16];
    #pragma unroll
    for (int c = 0; c < 16; ++c) hv[c] = hp[c * 256];

    unsigned stale = 0;
    #pragma unroll
    for (int c = 0; c < 16; ++c) {
      unsigned bad = (((unsigned)hv[c][0] ^ tagp) | ((unsigned)hv[c][1] ^ tagp) |
                      ((unsigned)hv[c][2] ^ tagp) | ((unsigned)hv[c][3] ^ tagp)) & 0xFFFF0000u;
      if (bad) stale |= (1u << c);
      else {
        i32x2 pk;
        pk[0] = (int)__builtin_amdgcn_perm((unsigned)hv[c][1], (unsigned)hv[c][0], 0x05040100u);
        pk[1] = (int)__builtin_amdgcn_perm((unsigned)hv[c][3], (unsigned)hv[c][2], 0x05040100u);
        ((i32x2*)hA)[c * 256 + tid] = pk;
      }
    }
    // ---- escalation: only stale chunks, coherent bypass path ----
    while (__any(stale != 0)) {
      #pragma unroll
      for (int c = 0; c < 16; ++c) if (stale & (1u << c)) {
        asm volatile("global_load_dwordx4 %0, %1, %2 sc0 sc1"
                     : "=v"(hv[c]) : "v"(voff), "s"((const void*)(hb + c * 1024)));
      }
      asm volatile("s_waitcnt vmcnt(0)" ::: "memory");
      __builtin_amdgcn_sched_barrier(0);
      #pragma unroll
      for (int c = 0; c < 16; ++c) if (stale & (1u << c)) {
        unsigned bad = (((unsigned)hv[c][0] ^ tagp) | ((unsigned)hv[c][1] ^ tagp) |
                        ((unsigned)hv[c][2] ^ tagp) | ((unsigned)hv[c][3] ^ tagp)) & 0xFFFF0000u;
        if (!bad) {
          i32x2 pk;
          pk[0] = (int)__builtin_amdgcn_perm((unsigned)hv[c][1], (unsigned)hv[c][0], 0x05040100u);
          pk[1] = (int)__builtin_amdgcn_perm((unsigned)hv[c][3], (unsigned)hv[c][2], 0x05040100u);
          ((i32x2*)hA)[c * 256 + tid] = pk;
          stale &= ~(1u << c);
        }
      }
    }
    __syncthreads();

    // consume gi(t) from pg0; shift pg1->pg0; issue gi(t+2) into pg1
    float gr  = __uint_as_float((unsigned)pgr0 << 16);
    float gz  = __uint_as_float((unsigned)pgz0 << 16);
    float gn_ = __uint_as_float((unsigned)pgn0 << 16);
    pgr0 = pgr1; pgz0 = pgz1; pgn0 = pgn1;
    {
      int t2 = (t + 2 < TT) ? (t + 2) : (TT - 1);
      size_t gb = ((size_t)(t2 * 4 + eg) * 64 + jg) * 768;
      pgr1 = g_gi[gb + tid]; pgz1 = g_gi[gb + 256 + tid]; pgn1 = g_gi[gb + 512 + tid];
    }

    // ---- h-GEMM: wave w3 in {0,1,2} computes gate tile (r, z, h_n) ----
    if (w3 < 3) {
      const bf16x8* ap = (const bf16x8*)hA;
      const bf16x8* bp = (const bf16x8*)whhL + (size_t)w3 * 2048;
      f32x4 a0 = {0.f,0.f,0.f,0.f}, a1 = {0.f,0.f,0.f,0.f};
      f32x4 a2 = {0.f,0.f,0.f,0.f}, a3 = {0.f,0.f,0.f,0.f};
      #pragma unroll 8
      for (int kk = 0; kk < 8; ++kk) {
        a0 = __builtin_amdgcn_mfma_f32_16x16x32_bf16(ap[kk * 64 + l],        bp[kk * 64 + l],        a0, 0, 0, 0);
        a1 = __builtin_amdgcn_mfma_f32_16x16x32_bf16(ap[(kk + 8) * 64 + l],  bp[(kk + 8) * 64 + l],  a1, 0, 0, 0);
        a2 = __builtin_amdgcn_mfma_f32_16x16x32_bf16(ap[(kk + 16) * 64 + l], bp[(kk + 16) * 64 + l], a2, 0, 0, 0);
        a3 = __builtin_amdgcn_mfma_f32_16x16x32_bf16(ap[(kk + 24) * 64 + l], bp[(kk + 24) * 64 + l], a3, 0, 0, 0);
      }
      f32x4 s;
      #pragma unroll
      for (int i = 0; i < 4; ++i) s[i] = (a0[i] + a1[i]) + (a2[i] + a3[i]);
      int col = l & 15, r0 = (l >> 4) * 4;
      #pragma unroll
      for (int i = 0; i < 4; ++i) Cl[w3 * 256 + (r0 + i) * 16 + col] = s[i];
    }
    __syncthreads();

    // ---- elementwise GRU update; publish h(t+1) fire-and-forget ----
    {
      float pr = gr + Cl[tid] + br;
      float pz = gz + Cl[256 + tid] + bz;
      float r = 1.f / (1.f + __expf(-pr));
      float z = 1.f / (1.f + __expf(-pz));
      float hn = Cl[512 + tid] + bhn;
      float gn = gn_ + bin + r * hn;
      float e2g = __expf(2.f * gn);
      float n = 1.f - 2.f / (e2g + 1.f);
      float hnew = (1.f - z) * n + z * hreg;

      if (t + 1 < TT) {
        float hm = hnew * mnext;
        hreg = hm;
        unsigned tw = ((unsigned)(t + 2) << 16) | (unsigned)f2bf(hm);
        unsigned* dst = g_hbuf32 + ((((size_t)((t + 1) & (NSLOT - 1))) * 4 + eg) << 14) + widx;
        asm volatile("global_store_dword %0, %1, off sc0 sc1" :: "v"(dst), "v"(tw) : "memory");
      }

      out[(size_t)t * NN * HH + (size_t)(e0 + e_) * HH + j] = hnew;
      if (t == TT - 1)
        out[(size_t)TT * NN * HH + (size_t)(e0 + e_) * HH + j] = hnew;
    }
  }
}

extern "C" void kernel_launch(void* const* d_in, const int* in_sizes, int n_in,
                              void* d_out, int out_size, void* d_ws, size_t ws_size,
                              hipStream_t stream) {
  (void)in_sizes; (void)n_in; (void)d_ws; (void)ws_size; (void)out_size;
  const float* x    = (const float*)d_in[0];
  const float* hx   = (const float*)d_in[1];
  const float* mask = (const float*)d_in[2];
  const float* wih  = (const float*)d_in[3];
  const float* whh  = (const float*)d_in[4];
  const float* bih  = (const float*)d_in[5];
  const float* bhh  = (const float*)d_in[6];
  float* out = (float*)d_out;

  hipFuncSetAttribute((const void*)gemm_gi, hipFuncAttributeMaxDynamicSharedMemorySize, 65536);
  hipFuncSetAttribute((const void*)scan_kernel, hipFuncAttributeMaxDynamicSharedMemorySize, 134144);

  prep_kernel<<<2048, 256, 0, stream>>>(x, wih, whh);
  gemm_gi<<<6144, 256, 65536, stream>>>();
  scan_kernel<<<256, 256, 134144, stream>>>(hx, mask, bih, bhh, out);
}

// Round 12
// 1928.703 us; speedup vs baseline: 2.8342x; 2.5046x over previous
//
#include <hip/hip_runtime.h>

#define TT 512
#define NN 64
#define DD 1024
#define HH 1024
#define NSLOT 32

typedef __attribute__((ext_vector_type(8))) short bf16x8;
typedef __attribute__((ext_vector_type(4))) float f32x4;
typedef __attribute__((ext_vector_type(8))) unsigned short u16x8;
typedef __attribute__((ext_vector_type(4))) int i32x4;
typedef __attribute__((ext_vector_type(2))) int i32x2;

// ---- static device buffers (rewritten every launch by prep/gemm) ----
// fragment-tiled bf16: vec8 idx = (tile*32 + kk)*64 + lane, elem e:
//   matrix[col = tile*16 + (lane&15)][k = kk*32 + (lane>>4)*8 + e]
__device__ unsigned short g_wih[192u * 2048 * 8];            // 6 MB
__device__ unsigned short g_whh[192u * 2048 * 8];            // 6 MB
__device__ unsigned short g_x[2048u * 2048 * 8];             // 67 MB, tile=(t*4+eg)
// gi (x-projection, bf16): [(t*4+eg)*64 + jg][gate][env16][jj16]
__device__ unsigned short g_gi[(size_t)2048 * 64 * 768];     // 201 MB
// tagged h state, NSLOT rotating slots: word=(tag<<16)|bf16(h); [slot][eg][16384]
__device__ unsigned g_hbuf32[(size_t)NSLOT * 4 * 16384];     // 8 MB

__device__ __forceinline__ unsigned short f2bf(float f) {
  unsigned u = __float_as_uint(f);
  u += 0x7fffu + ((u >> 16) & 1u);
  return (unsigned short)(u >> 16);
}

__global__ void prep_kernel(const float* __restrict__ x,
                            const float* __restrict__ wih,
                            const float* __restrict__ whh) {
  const int gsz = gridDim.x * blockDim.x;
  const int gid = blockIdx.x * blockDim.x + threadIdx.x;
  // zero the rotating tag buffer (tag 0 = invalid; live tags are 1..513)
  for (int z = gid; z < NSLOT * 4 * 16384; z += gsz) g_hbuf32[z] = 0u;

  const int W8 = 192 * 2048;          // vec8 groups per weight matrix
  const int X8 = 2048 * 2048;         // vec8 groups for x
  for (int idx = gid; idx < 2 * W8 + X8; idx += gsz) {
    if (idx < 2 * W8) {
      const float* src = (idx < W8) ? wih : whh;
      unsigned short* dst = (idx < W8) ? g_wih : g_whh;
      int i8 = (idx < W8) ? idx : idx - W8;
      size_t g = (size_t)i8 * 8;
      int col = (int)(g >> 10);
      int k = (int)(g & 1023);
      int kk = k >> 5, lg = (k >> 3) & 3;
      int cg = col >> 4;
      int l = (col & 15) | (lg << 4);
      size_t o8 = ((size_t)cg * 32 + kk) * 64 + l;
      const float* p = src + g;
      float4 v0 = *(const float4*)(p);
      float4 v1 = *(const float4*)(p + 4);
      u16x8 u;
      u[0] = f2bf(v0.x); u[1] = f2bf(v0.y); u[2] = f2bf(v0.z); u[3] = f2bf(v0.w);
      u[4] = f2bf(v1.x); u[5] = f2bf(v1.y); u[6] = f2bf(v1.z); u[7] = f2bf(v1.w);
      *(u16x8*)(dst + o8 * 8) = u;
    } else {
      int i8 = idx - 2 * W8;
      size_t g = (size_t)i8 * 8;
      int row = (int)(g >> 10);             // t*64 + env
      int k = (int)(g & 1023);
      int t = row >> 6, env = row & 63;
      int eg = env >> 4;
      int kk = k >> 5, lg = (k >> 3) & 3;
      int l = (env & 15) | (lg << 4);
      size_t o8 = (((size_t)t * 4 + eg) * 32 + kk) * 64 + l;
      const float* p = x + g;
      float4 v0 = *(const float4*)(p);
      float4 v1 = *(const float4*)(p + 4);
      u16x8 u;
      u[0] = f2bf(v0.x); u[1] = f2bf(v0.y); u[2] = f2bf(v0.z); u[3] = f2bf(v0.w);
      u[4] = f2bf(v1.x); u[5] = f2bf(v1.y); u[6] = f2bf(v1.z); u[7] = f2bf(v1.w);
      *(u16x8*)(g_x + o8 * 8) = u;
    }
  }
}

// ---- gi = x * wih^T, 128x128 tile, BK=128, reg-prefetch + LDS ----
__global__ __launch_bounds__(256) void gemm_gi() {
  extern __shared__ char smem[];
  unsigned short* As = (unsigned short*)smem;      // 32KB
  unsigned short* Bs = As + 2048 * 8;              // 32KB
  const int tid = threadIdx.x;
  const int bid = blockIdx.x;
  const int mblk = bid & 255, nblk = bid >> 8;     // 256 x 24
  const int w = tid >> 6, l = tid & 63;
  const int wm = w >> 1, wn = w & 1;

  u16x8 pa[8], pb[8];
  #pragma unroll
  for (int i = 0; i < 8; ++i) {
    int e = tid + i * 256;
    int mt = e >> 8, kkl = (e >> 6) & 3, lane = e & 63;
    pa[i] = *((const u16x8*)g_x  + ((size_t)(mblk * 8 + mt) * 32 + kkl) * 64 + lane);
    pb[i] = *((const u16x8*)g_wih + ((size_t)(nblk * 8 + mt) * 32 + kkl) * 64 + lane);
  }
  f32x4 acc[4][4] = {};
  for (int c = 0; c < 8; ++c) {
    __syncthreads();
    #pragma unroll
    for (int i = 0; i < 8; ++i) {
      int e = tid + i * 256;
      ((u16x8*)As)[e] = pa[i];
      ((u16x8*)Bs)[e] = pb[i];
    }
    __syncthreads();
    if (c < 7) {
      #pragma unroll
      for (int i = 0; i < 8; ++i) {
        int e = tid + i * 256;
        int mt = e >> 8, kkl = (e >> 6) & 3, lane = e & 63;
        pa[i] = *((const u16x8*)g_x  + ((size_t)(mblk * 8 + mt) * 32 + (c + 1) * 4 + kkl) * 64 + lane);
        pb[i] = *((const u16x8*)g_wih + ((size_t)(nblk * 8 + mt) * 32 + (c + 1) * 4 + kkl) * 64 + lane);
      }
    }
    #pragma unroll
    for (int kkl = 0; kkl < 4; ++kkl) {
      bf16x8 af[4], bfr[4];
      #pragma unroll
      for (int ai = 0; ai < 4; ++ai) af[ai]  = ((const bf16x8*)As)[((wm * 4 + ai) * 4 + kkl) * 64 + l];
      #pragma unroll
      for (int bi = 0; bi < 4; ++bi) bfr[bi] = ((const bf16x8*)Bs)[((wn * 4 + bi) * 4 + kkl) * 64 + l];
      #pragma unroll
      for (int ai = 0; ai < 4; ++ai)
        #pragma unroll
        for (int bi = 0; bi < 4; ++bi)
          acc[ai][bi] = __builtin_amdgcn_mfma_f32_16x16x32_bf16(af[ai], bfr[bi], acc[ai][bi], 0, 0, 0);
    }
  }
  const int jj = l & 15;
  #pragma unroll
  for (int ai = 0; ai < 4; ++ai)
    #pragma unroll
    for (int bi = 0; bi < 4; ++bi) {
      int mt = mblk * 8 + wm * 4 + ai;       // = t*4+eg
      int nt = nblk * 8 + wn * 4 + bi;
      int gate = nt >> 6, jg = nt & 63;
      size_t base = ((size_t)mt * 64 + jg) * 768 + (size_t)gate * 256;
      #pragma unroll
      for (int i = 0; i < 4; ++i) {
        int env = (l >> 4) * 4 + i;
        g_gi[base + env * 16 + jj] = f2bf(acc[ai][bi][i]);
      }
    }
}

// ---- persistent scan: 256 wgs = (eg 0..3) x (jg 0..63), 1 wg/CU ----
// eg-clustered XCD swizzle (perf-only): XCDs {2eg,2eg+1} host all 64 wgs
// of one eg -> 32-way L2 sharing of the h bulk read instead of 8-way.
__global__ __launch_bounds__(256) void scan_kernel(const float* __restrict__ hx,
                                                   const float* __restrict__ mask,
                                                   const float* __restrict__ bih,
                                                   const float* __restrict__ bhh,
                                                   float* __restrict__ out) {
  extern __shared__ char smem[];
  unsigned short* whhL = (unsigned short*)smem;          // 96KB
  unsigned short* hA   = whhL + 3 * 2048 * 8;            // 32KB
  float* Cl = (float*)(hA + 2048 * 8);                   // 3KB

  const int tid = threadIdx.x;
  const int bid = blockIdx.x;
  const int eg = (bid & 7) >> 1;                   // bijective swizzle (r5)
  const int jg = ((bid >> 3) << 1) | (bid & 1);
  const int e0 = eg * 16;
  const int w3 = tid >> 6, l = tid & 63;
  const int e_ = tid >> 4, jj = tid & 15;
  const int j = jg * 16 + jj;

  // preload W_hh j-slice into LDS (gates r,z,n)
  #pragma unroll 4
  for (int i = 0; i < 24; ++i) {
    int e = tid + i * 256;                   // < 6144
    int gate = e >> 11, rem = e & 2047;
    ((u16x8*)whhL)[e] = *((const u16x8*)g_whh + (size_t)(gate * 64 + jg) * 2048 + rem);
  }

  // producer word index for this thread's h[e0+e_][j] in fragment order.
  // Closed form: tid 0 of producer wg jg' lands at word 256*jg' (poll target).
  const int kf = jg * 16 + jj;
  const int widx = (((kf >> 5) * 64) + (e_ | (((kf >> 3) & 3) << 4))) * 8 + (kf & 7);

  // publish h0 = hx*mask[0] with tag 1 into slot 0 (fire-and-forget)
  float hreg;
  {
    float h0 = hx[(size_t)(e0 + e_) * HH + j] * mask[e0 + e_];
    hreg = h0;
    unsigned tw = (1u << 16) | (unsigned)f2bf(h0);
    unsigned* dst = g_hbuf32 + ((size_t)eg << 14) + widx;
    asm volatile("global_store_dword %0, %1, off sc0 sc1" :: "v"(dst), "v"(tw) : "memory");
  }

  const float br  = bih[j] + bhh[j];
  const float bz  = bih[HH + j] + bhh[HH + j];
  const float bin = bih[2 * HH + j];
  const float bhn = bhh[2 * HH + j];

  // gi prefetch, depth 2 (pg0 = step t, pg1 = step t+1)
  unsigned short pgr0, pgz0, pgn0, pgr1, pgz1, pgn1;
  {
    size_t gb0 = ((size_t)eg * 64 + jg) * 768;
    pgr0 = g_gi[gb0 + tid]; pgz0 = g_gi[gb0 + 256 + tid]; pgn0 = g_gi[gb0 + 512 + tid];
    size_t gb1 = ((size_t)(4 + eg) * 64 + jg) * 768;
    pgr1 = g_gi[gb1 + tid]; pgz1 = g_gi[gb1 + 256 + tid]; pgn1 = g_gi[gb1 + 512 + tid];
  }

  const unsigned voff = (unsigned)tid * 16;  // byte offset for dwordx4

  for (int t = 0; t < TT; ++t) {
    int tm = (t + 1 < TT) ? (t + 1) : (TT - 1);
    float mnext = mask[tm * NN + e0 + e_];

    const int slot = t & (NSLOT - 1);
    const unsigned* hb = g_hbuf32 + (((size_t)slot * 4 + eg) << 14);
    const unsigned tagc = (unsigned)(t + 1);

    // ---- poll the DATA, all 4 waves (staggered samplers — r10/r11 showed
    //      single-wave+LDS-broadcast costs ~3us/step in detection latency) ----
    {
      const unsigned* pp = hb + (l << 8);
      while (true) {
        unsigned v;
        asm volatile("global_load_dword %0, %1, off sc0 sc1\n\t"
                     "s_waitcnt vmcnt(0)"
                     : "=v"(v) : "v"(pp) : "memory");
        if (__all((v >> 16) >= tagc)) break;
        __builtin_amdgcn_s_sleep(1);
      }
      __builtin_amdgcn_sched_barrier(0);
    }

    // ---- attempt 1: PLAIN cached bulk read (L2-shared, 32 wgs/XCD-pair) ----
    const unsigned tagp = tagc << 16;
    const i32x4* hp = (const i32x4*)hb + tid;
    i32x4 hv[16];
    #pragma unroll
    for (int c = 0; c < 16; ++c) hv[c] = hp[c * 256];

    unsigned stale = 0;
    #pragma unroll
    for (int c = 0; c < 16; ++c) {
      unsigned bad = (((unsigned)hv[c][0] ^ tagp) | ((unsigned)hv[c][1] ^ tagp) |
                      ((unsigned)hv[c][2] ^ tagp) | ((unsigned)hv[c][3] ^ tagp)) & 0xFFFF0000u;
      if (bad) stale |= (1u << c);
      else {
        i32x2 pk;
        pk[0] = (int)__builtin_amdgcn_perm((unsigned)hv[c][1], (unsigned)hv[c][0], 0x05040100u);
        pk[1] = (int)__builtin_amdgcn_perm((unsigned)hv[c][3], (unsigned)hv[c][2], 0x05040100u);
        ((i32x2*)hA)[c * 256 + tid] = pk;
      }
    }
    // ---- escalation: only stale chunks, coherent bypass path ----
    while (__any(stale != 0)) {
      #pragma unroll
      for (int c = 0; c < 16; ++c) if (stale & (1u << c)) {
        asm volatile("global_load_dwordx4 %0, %1, %2 sc0 sc1"
                     : "=v"(hv[c]) : "v"(voff), "s"((const void*)(hb + c * 1024)));
      }
      asm volatile("s_waitcnt vmcnt(0)" ::: "memory");
      __builtin_amdgcn_sched_barrier(0);
      #pragma unroll
      for (int c = 0; c < 16; ++c) if (stale & (1u << c)) {
        unsigned bad = (((unsigned)hv[c][0] ^ tagp) | ((unsigned)hv[c][1] ^ tagp) |
                        ((unsigned)hv[c][2] ^ tagp) | ((unsigned)hv[c][3] ^ tagp)) & 0xFFFF0000u;
        if (!bad) {
          i32x2 pk;
          pk[0] = (int)__builtin_amdgcn_perm((unsigned)hv[c][1], (unsigned)hv[c][0], 0x05040100u);
          pk[1] = (int)__builtin_amdgcn_perm((unsigned)hv[c][3], (unsigned)hv[c][2], 0x05040100u);
          ((i32x2*)hA)[c * 256 + tid] = pk;
          stale &= ~(1u << c);
        }
      }
    }
    __syncthreads();

    // consume gi(t) from pg0; shift pg1->pg0; issue gi(t+2) into pg1
    float gr  = __uint_as_float((unsigned)pgr0 << 16);
    float gz  = __uint_as_float((unsigned)pgz0 << 16);
    float gn_ = __uint_as_float((unsigned)pgn0 << 16);
    pgr0 = pgr1; pgz0 = pgz1; pgn0 = pgn1;
    {
      int t2 = (t + 2 < TT) ? (t + 2) : (TT - 1);
      size_t gb = ((size_t)(t2 * 4 + eg) * 64 + jg) * 768;
      pgr1 = g_gi[gb + tid]; pgz1 = g_gi[gb + 256 + tid]; pgn1 = g_gi[gb + 512 + tid];
    }

    // ---- h-GEMM: wave w3 in {0,1,2} computes gate tile (r, z, h_n) ----
    if (w3 < 3) {
      const bf16x8* ap = (const bf16x8*)hA;
      const bf16x8* bp = (const bf16x8*)whhL + (size_t)w3 * 2048;
      f32x4 a0 = {0.f,0.f,0.f,0.f}, a1 = {0.f,0.f,0.f,0.f};
      f32x4 a2 = {0.f,0.f,0.f,0.f}, a3 = {0.f,0.f,0.f,0.f};
      #pragma unroll 8
      for (int kk = 0; kk < 8; ++kk) {
        a0 = __builtin_amdgcn_mfma_f32_16x16x32_bf16(ap[kk * 64 + l],        bp[kk * 64 + l],        a0, 0, 0, 0);
        a1 = __builtin_amdgcn_mfma_f32_16x16x32_bf16(ap[(kk + 8) * 64 + l],  bp[(kk + 8) * 64 + l],  a1, 0, 0, 0);
        a2 = __builtin_amdgcn_mfma_f32_16x16x32_bf16(ap[(kk + 16) * 64 + l], bp[(kk + 16) * 64 + l], a2, 0, 0, 0);
        a3 = __builtin_amdgcn_mfma_f32_16x16x32_bf16(ap[(kk + 24) * 64 + l], bp[(kk + 24) * 64 + l], a3, 0, 0, 0);
      }
      f32x4 s;
      #pragma unroll
      for (int i = 0; i < 4; ++i) s[i] = (a0[i] + a1[i]) + (a2[i] + a3[i]);
      int col = l & 15, r0 = (l >> 4) * 4;
      #pragma unroll
      for (int i = 0; i < 4; ++i) Cl[w3 * 256 + (r0 + i) * 16 + col] = s[i];
    }
    __syncthreads();

    // ---- elementwise GRU update; publish h(t+1) fire-and-forget ----
    {
      float pr = gr + Cl[tid] + br;
      float pz = gz + Cl[256 + tid] + bz;
      float r = 1.f / (1.f + __expf(-pr));
      float z = 1.f / (1.f + __expf(-pz));
      float hn = Cl[512 + tid] + bhn;
      float gn = gn_ + bin + r * hn;
      float e2g = __expf(2.f * gn);
      float n = 1.f - 2.f / (e2g + 1.f);
      float hnew = (1.f - z) * n + z * hreg;

      if (t + 1 < TT) {
        float hm = hnew * mnext;
        hreg = hm;
        unsigned tw = ((unsigned)(t + 2) << 16) | (unsigned)f2bf(hm);
        unsigned* dst = g_hbuf32 + ((((size_t)((t + 1) & (NSLOT - 1))) * 4 + eg) << 14) + widx;
        asm volatile("global_store_dword %0, %1, off sc0 sc1" :: "v"(dst), "v"(tw) : "memory");
      }

      out[(size_t)t * NN * HH + (size_t)(e0 + e_) * HH + j] = hnew;
      if (t == TT - 1)
        out[(size_t)TT * NN * HH + (size_t)(e0 + e_) * HH + j] = hnew;
    }
  }
}

extern "C" void kernel_launch(void* const* d_in, const int* in_sizes, int n_in,
                              void* d_out, int out_size, void* d_ws, size_t ws_size,
                              hipStream_t stream) {
  (void)in_sizes; (void)n_in; (void)d_ws; (void)ws_size; (void)out_size;
  const float* x    = (const float*)d_in[0];
  const float* hx   = (const float*)d_in[1];
  const float* mask = (const float*)d_in[2];
  const float* wih  = (const float*)d_in[3];
  const float* whh  = (const float*)d_in[4];
  const float* bih  = (const float*)d_in[5];
  const float* bhh  = (const float*)d_in[6];
  float* out = (float*)d_out;

  hipFuncSetAttribute((const void*)gemm_gi, hipFuncAttributeMaxDynamicSharedMemorySize, 65536);
  hipFuncSetAttribute((const void*)scan_kernel, hipFuncAttributeMaxDynamicSharedMemorySize, 134144);

  prep_kernel<<<2048, 256, 0, stream>>>(x, wih, whh);
  gemm_gi<<<6144, 256, 65536, stream>>>();
  scan_kernel<<<256, 256, 134144, stream>>>(hx, mask, bih, bhh, out);
}